// Round 8
// baseline (128.791 us; speedup 1.0000x reference)
//
#include <hip/hip_runtime.h>
#include <hip/hip_bf16.h>

// Problem constants
#define B_   2
#define N_   4096
#define DIM_ 768
#define H_   8
#define MROWS_ 8192   // B_*N_

typedef __bf16 bf16x8 __attribute__((ext_vector_type(8)));
typedef __bf16 bf16x4 __attribute__((ext_vector_type(4)));
typedef float  f32x4  __attribute__((ext_vector_type(4)));

static __device__ __forceinline__ f32x4 mfma16(bf16x8 a, bf16x8 b, f32x4 c) {
    return __builtin_amdgcn_mfma_f32_16x16x32_bf16(a, b, c, 0, 0, 0);
}

// async global->LDS, 16B per lane. LDS dst is wave-uniform base + lane*16.
#define GLDS16(g, l) \
    __builtin_amdgcn_global_load_lds((const __attribute__((address_space(1))) void*)(g), \
                                     (__attribute__((address_space(3))) void*)(l), 16, 0, 0)

// ---------------------------------------------------------------------------
// Kernel 1: x (fp32) -> xb (bf16), vectorized 4/thread
__global__ void cvt_x_kernel(const float* __restrict__ x, __bf16* __restrict__ xb, int n4) {
    int i = blockIdx.x * blockDim.x + threadIdx.x;
    if (i >= n4) return;
    float4 f = reinterpret_cast<const float4*>(x)[i];
    bf16x4 o;
    o[0] = (__bf16)f.x; o[1] = (__bf16)f.y; o[2] = (__bf16)f.z; o[3] = (__bf16)f.w;
    reinterpret_cast<bf16x4*>(xb)[i] = o;
}

// ---------------------------------------------------------------------------
// Kernel 2: LDS-tiled 64x64 transpose of weights -> bf16.
__global__ __launch_bounds__(256) void transpose_w_kernel(const float* __restrict__ Wq,
                                                          const float* __restrict__ Wk,
                                                          const float* __restrict__ Wv,
                                                          const float* __restrict__ Wo,
                                                          __bf16* __restrict__ wt,
                                                          __bf16* __restrict__ wot) {
    __shared__ float tile[64][65];
    const int bix = blockIdx.x;
    const float* src;
    int src_ld, rbase, cbase, dst_ld, drow, dcol;
    __bf16* dst;
    if (bix < 288) {                       // Wq/Wk/Wv: [768][512]
        int m = bix / 96, t = bix - m * 96;
        int tr = t >> 3, tc = t & 7;
        src = (m == 0) ? Wq : ((m == 1) ? Wk : Wv);
        src_ld = 512; rbase = tr * 64; cbase = tc * 64;
        dst = wt; dst_ld = 768; drow = m * 512 + tc * 64; dcol = tr * 64;
    } else {                               // Wo: [512][768]
        int t = bix - 288;
        int tr = t / 12, tc = t - tr * 12;
        src = Wo; src_ld = 768; rbase = tr * 64; cbase = tc * 64;
        dst = wot; dst_ld = 512; drow = tc * 64; dcol = tr * 64;
    }
#pragma unroll
    for (int kk = 0; kk < 4; ++kk) {
        int idx = threadIdx.x + kk * 256;
        int r = idx >> 4, c = (idx & 15) << 2;
        float4 f = *reinterpret_cast<const float4*>(&src[(size_t)(rbase + r) * src_ld + cbase + c]);
        tile[r][c] = f.x; tile[r][c + 1] = f.y; tile[r][c + 2] = f.z; tile[r][c + 3] = f.w;
    }
    __syncthreads();
#pragma unroll
    for (int kk = 0; kk < 4; ++kk) {
        int idx = threadIdx.x + kk * 256;
        int r = idx >> 4, c = (idx & 15) << 2;
        bf16x4 ov;
        ov[0] = (__bf16)tile[c][r];     ov[1] = (__bf16)tile[c + 1][r];
        ov[2] = (__bf16)tile[c + 2][r]; ov[3] = (__bf16)tile[c + 3][r];
        *reinterpret_cast<bf16x4*>(&dst[(size_t)(drow + r) * dst_ld + dcol + c]) = ov;
    }
}

// ---------------------------------------------------------------------------
// m97-structure GEMM main loop: 128x128 tile, BK=32, 4 waves (2x2 of 64x64),
// global_load_lds(16B) double-buffered staging, 2-phase pipeline.
template<int KSTEPS>
__device__ __forceinline__ void gemm_tile_main(const __bf16* __restrict__ A, const int lda,
                                               const int arow0,
                                               const __bf16* __restrict__ Bt, const int ldb,
                                               const int bcol0,
                                               __bf16* __restrict__ abuf,
                                               __bf16* __restrict__ bbuf,
                                               f32x4 (&acc)[4][4]) {
    const int lane = threadIdx.x & 63, wave = threadIdx.x >> 6;
    const int lr = lane & 15, lg = lane >> 4;
    const int wr = wave >> 1, wc = wave & 1;

    const int cid0 = wave * 128 + lane;
    const int cid1 = cid0 + 64;
    const __bf16* sA0 = A  + (size_t)(arow0 + (cid0 >> 2)) * lda + (cid0 & 3) * 8;
    const __bf16* sA1 = A  + (size_t)(arow0 + (cid1 >> 2)) * lda + (cid1 & 3) * 8;
    const __bf16* sB0 = Bt + (size_t)(bcol0 + (cid0 >> 2)) * ldb + (cid0 & 3) * 8;
    const __bf16* sB1 = Bt + (size_t)(bcol0 + (cid1 >> 2)) * ldb + (cid1 & 3) * 8;

    auto stage = [&](int buf, int ks) {
        __bf16* da = abuf + buf * 4096 + wave * 1024;
        __bf16* db = bbuf + buf * 4096 + wave * 1024;
        GLDS16(sA0 + ks * 32, da);
        GLDS16(sA1 + ks * 32, da + 512);
        GLDS16(sB0 + ks * 32, db);
        GLDS16(sB1 + ks * 32, db + 512);
    };

    stage(0, 0);
    asm volatile("s_waitcnt vmcnt(0)" ::: "memory");
    __syncthreads();

    const int ar_off = (wr * 64 + lr) * 32 + lg * 8;
    const int br_off = (wc * 64 + lr) * 32 + lg * 8;

    int buf = 0;
    for (int ks = 0; ks < KSTEPS; ++ks) {
        if (ks + 1 < KSTEPS) stage(buf ^ 1, ks + 1);
        const __bf16* ab = abuf + buf * 4096 + ar_off;
        const __bf16* bb = bbuf + buf * 4096 + br_off;
        bf16x8 af[4], bfr[4];
#pragma unroll
        for (int m = 0; m < 4; ++m) af[m] = *reinterpret_cast<const bf16x8*>(ab + m * 512);
#pragma unroll
        for (int n = 0; n < 4; ++n) bfr[n] = *reinterpret_cast<const bf16x8*>(bb + n * 512);
#pragma unroll
        for (int m = 0; m < 4; ++m)
#pragma unroll
            for (int n = 0; n < 4; ++n)
                acc[m][n] = mfma16(af[m], bfr[n], acc[m][n]);
        asm volatile("s_waitcnt vmcnt(0)" ::: "memory");
        __syncthreads();
        buf ^= 1;
    }
}

// ---------------------------------------------------------------------------
// Kernel 3: QKV projection GEMM. 768 blocks (XCD-chunked).
// Q pre-scaled by 0.125*log2(e) (attention uses exp2). V transposed [B,H,64,N].
__global__ __launch_bounds__(256) void qkv_gemm_kernel(const __bf16* __restrict__ xb,
                                                       const __bf16* __restrict__ wt,
                                                       __bf16* __restrict__ q,
                                                       __bf16* __restrict__ k,
                                                       __bf16* __restrict__ vt) {
    __shared__ __align__(16) __bf16 abuf[2 * 4096];
    __shared__ __align__(16) __bf16 bbuf[2 * 4096];

    const int bid = blockIdx.x;
    const int vb = (bid & 7) * 96 + (bid >> 3);
    const int by = vb % 12, bx = vb / 12;

    f32x4 acc[4][4] = {};
    gemm_tile_main<24>(xb, 768, bx * 128, wt, 768, by * 128, abuf, bbuf, acc);

    const int lane = threadIdx.x & 63, wave = threadIdx.x >> 6;
    const int lr = lane & 15, lg = lane >> 4;
    const int wr = wave >> 1, wc = wave & 1;
    const int bi = (bx * 128) >> 12;
    const int nbase = (bx * 128) & 4095;

    const float QSCALE = 0.125f * 1.44269504089f;   // fold log2(e): softmax uses exp2

#pragma unroll
    for (int n = 0; n < 4; ++n) {
        const int col0 = by * 128 + wc * 64 + n * 16;
        const int mtx = col0 >> 9;
        const int h   = (col0 >> 6) & 7;
        const int d0  = (col0 & 63) + lr;
        const size_t hb = (size_t)(bi * 8 + h);
#pragma unroll
        for (int m = 0; m < 4; ++m) {
            const int nn = nbase + wr * 64 + m * 16 + lg * 4;
            if (mtx == 0) {
#pragma unroll
                for (int r = 0; r < 4; ++r)
                    q[(hb * 4096 + nn + r) * 64 + d0] = (__bf16)(acc[m][n][r] * QSCALE);
            } else if (mtx == 1) {
#pragma unroll
                for (int r = 0; r < 4; ++r)
                    k[(hb * 4096 + nn + r) * 64 + d0] = (__bf16)acc[m][n][r];
            } else {
                bf16x4 ov;
#pragma unroll
                for (int r = 0; r < 4; ++r) ov[r] = (__bf16)acc[m][n][r];
                *reinterpret_cast<bf16x4*>(&vt[(hb * 64 + d0) * 4096 + nn]) = ov;
            }
        }
    }
}

// ---------------------------------------------------------------------------
// Kernel 4: flash attention, P in-register (sigma-permuted K staging),
// 2-tile super-periods: one vmcnt(0)+s_barrier per TWO k-tiles (33 barriers
// vs 65). A/B software pipeline threads through: EXP(prev)||QK(cur)||PV(prev).
// V staged one tile behind K so rd/wr buffer halves never overlap.
__global__ __launch_bounds__(256) void attn_kernel(const __bf16* __restrict__ q,
                                                   const __bf16* __restrict__ k,
                                                   const __bf16* __restrict__ vt,
                                                   __bf16* __restrict__ o) {
    const int lane = threadIdx.x & 63, wave = threadIdx.x >> 6;
    const int lr = lane & 15, lg = lane >> 4;

    const int bid  = blockIdx.x;
    const int vbid = (bid & 7) * 64 + (bid >> 3);
    const int qtile = vbid & 31;
    const int bh    = vbid >> 5;
    const int qbase = qtile * 128 + wave * 32;

    const __bf16* Qh = q  + (size_t)bh * N_ * 64;
    const __bf16* Kh = k  + (size_t)bh * N_ * 64;
    const __bf16* Vh = vt + (size_t)bh * 64 * N_;

    // [buf][tile-in-pair][64][64] : 2*2*8KB = 32KB each
    __shared__ __align__(16) __bf16 kbuf[2][2][64][64];
    __shared__ __align__(16) __bf16 vbuf[2][2][64][64];
    __bf16* kb0 = &kbuf[0][0][0][0];
    __bf16* vb0 = &vbuf[0][0][0][0];

    const int l8 = lane >> 3, l7 = lane & 7;
    const int swz8 = (l7 ^ l8) * 8;

    // per-lane K source offsets: row sigma(i), chunk-swizzled (waves 0,1 stage K)
    int ksrc[4];
#pragma unroll
    for (int c = 0; c < 4; ++c) {
        int i = (wave & 1) * 32 + c * 8 + l8;
        int sig = ((i >> 4) & 1) * 32 + ((i >> 2) & 3) * 8 + ((i >> 5) & 1) * 4 + (i & 3);
        ksrc[c] = sig * 64 + swz8;
    }

    auto stageK1 = [&](__bf16* dstbase, int jt) {   // one K tile (4 loads, waves 0,1)
        if (wave < 2) {
            const __bf16* srcb = Kh + (size_t)jt * 4096;
            __bf16* dst = dstbase + (wave & 1) * 2048;
#pragma unroll
            for (int c = 0; c < 4; ++c)
                GLDS16(srcb + ksrc[c], dst + c * 512);
        }
    };
    auto stageV1 = [&](__bf16* dstbase, int jt) {   // one V tile (4 loads, waves 2,3)
        if (wave >= 2) {
            const int w2 = wave - 2;
            const __bf16* src = Vh + (size_t)(w2 * 32 + l8) * 4096 + jt * 64 + swz8;
            __bf16* dst = dstbase + w2 * 2048;
#pragma unroll
            for (int c = 0; c < 4; ++c)
                GLDS16(src + (size_t)c * 8 * 4096, dst + c * 512);
        }
    };

    bf16x8 qf[2][2];
#pragma unroll
    for (int frag = 0; frag < 2; ++frag)
#pragma unroll
        for (int kc = 0; kc < 2; ++kc)
            qf[frag][kc] = *reinterpret_cast<const bf16x8*>(
                Qh + (size_t)(qbase + frag * 16 + lr) * 64 + kc * 32 + lg * 8);

    f32x4 acc[2][4] = {};
    f32x4 accl[2] = {};
    bf16x8 vones;
#pragma unroll
    for (int t = 0; t < 8; ++t) vones[t] = (__bf16)1.0f;

    auto QK = [&](f32x4 (&s)[2][4], const __bf16* kb_) {
        const char* kb = (const char*)kb_;
        __builtin_amdgcn_s_setprio(1);
#pragma unroll
        for (int kc = 0; kc < 2; ++kc) {
#pragma unroll
            for (int cb = 0; cb < 4; ++cb) {
                const int row = cb * 16 + lr;
                bf16x8 bk = *reinterpret_cast<const bf16x8*>(
                    kb + row * 128 + (((kc * 4 + lg) ^ (lr & 7)) << 4));
                if (kc == 0) { s[0][cb] = mfma16(bk, qf[0][0], {}); s[1][cb] = mfma16(bk, qf[1][0], {}); }
                else         { s[0][cb] = mfma16(bk, qf[0][1], s[0][cb]); s[1][cb] = mfma16(bk, qf[1][1], s[1][cb]); }
            }
        }
        __builtin_amdgcn_s_setprio(0);
    };
    auto EXP = [&](f32x4 (&s)[2][4], bf16x8 (&pk)[2][2]) {
#pragma unroll
        for (int frag = 0; frag < 2; ++frag)
#pragma unroll
            for (int kc = 0; kc < 2; ++kc) {
#pragma unroll
                for (int t = 0; t < 8; ++t)
                    pk[frag][kc][t] = (__bf16)__builtin_amdgcn_exp2f(s[frag][kc + 2 * (t >> 2)][t & 3]);
                accl[frag] = mfma16(pk[frag][kc], vones, accl[frag]);   // lsum via matrix pipe
            }
    };
    auto PV = [&](bf16x8 (&pk)[2][2], const __bf16* vb_) {
        const char* vb = (const char*)vb_;
        __builtin_amdgcn_s_setprio(1);
#pragma unroll
        for (int kc = 0; kc < 2; ++kc) {
#pragma unroll
            for (int cbv = 0; cbv < 4; ++cbv) {
                const int row = cbv * 16 + lr;
                bf16x8 bv = *reinterpret_cast<const bf16x8*>(
                    vb + row * 128 + (((kc * 4 + lg) ^ (lr & 7)) << 4));
                acc[0][cbv] = mfma16(pk[0][kc], bv, acc[0][cbv]);
                acc[1][cbv] = mfma16(pk[1][kc], bv, acc[1][cbv]);
            }
        }
        __builtin_amdgcn_s_setprio(0);
    };

    f32x4 sA[2][4], sB[2][4];
    bf16x8 pkA[2][2], pkB[2][2];

    int rdo = 8192, wro = 0;   // period 0 reads buf[1], writes buf[0]

    // ---- prologue: kbuf[1] <- K{0,1}; vbuf[1][1] <- V0; drain all.
    stageK1(kb0 + 8192, 0);
    stageK1(kb0 + 8192 + 4096, 1);
    stageV1(vb0 + 8192 + 4096, 0);
    asm volatile("s_waitcnt vmcnt(0)" ::: "memory");
    __builtin_amdgcn_s_barrier();

    // ---- period 0 (tiles 0,1): no previous tile to finish.
    stageK1(kb0 + wro, 2);          stageK1(kb0 + wro + 4096, 3);
    stageV1(vb0 + wro, 1);          stageV1(vb0 + wro + 4096, 2);
    QK(sB, kb0 + rdo);
    EXP(sB, pkB);
    QK(sA, kb0 + rdo + 4096);
    PV(pkB, vb0 + rdo + 4096);
    asm volatile("s_waitcnt vmcnt(0)" ::: "memory");
    __builtin_amdgcn_s_barrier();
    rdo ^= 8192; wro ^= 8192;

    // ---- uniform periods P = 1..30 (tiles a=2P, b=2P+1)
    for (int P = 1; P <= 30; ++P) {
        const int a = 2 * P;
        stageK1(kb0 + wro, a + 2);      stageK1(kb0 + wro + 4096, a + 3);
        stageV1(vb0 + wro, a + 1);      stageV1(vb0 + wro + 4096, a + 2);
        EXP(sA, pkA);                    // tile a-1
        QK(sB, kb0 + rdo);               // tile a
        PV(pkA, vb0 + rdo);              // tile a-1
        EXP(sB, pkB);                    // tile a
        QK(sA, kb0 + rdo + 4096);        // tile a+1
        PV(pkB, vb0 + rdo + 4096);       // tile a
        asm volatile("s_waitcnt vmcnt(0)" ::: "memory");
        __builtin_amdgcn_s_barrier();
        rdo ^= 8192; wro ^= 8192;
    }

    // ---- period 31 (tiles 62,63): only V(63) left to stage.
    stageV1(vb0 + wro, 63);
    EXP(sA, pkA);                        // tile 61
    QK(sB, kb0 + rdo);                   // tile 62
    PV(pkA, vb0 + rdo);                  // tile 61
    EXP(sB, pkB);                        // tile 62
    QK(sA, kb0 + rdo + 4096);            // tile 63
    PV(pkB, vb0 + rdo + 4096);           // tile 62
    asm volatile("s_waitcnt vmcnt(0)" ::: "memory");
    __builtin_amdgcn_s_barrier();

    // ---- epilogue: finish tile 63 (V(63) at vb0 + wro, slot 0)
    EXP(sA, pkA);
    PV(pkA, vb0 + wro);

    // accl[frag][r] = lsum for q-row (frag*16 + lg*4 + r): no shuffles needed.
    const int b = bh >> 3, h = bh & 7;
#pragma unroll
    for (int frag = 0; frag < 2; ++frag) {
#pragma unroll
        for (int r = 0; r < 4; ++r) {
            float inv = 1.f / accl[frag][r];
            int row = b * N_ + qbase + frag * 16 + lg * 4 + r;
#pragma unroll
            for (int cbv = 0; cbv < 4; ++cbv)
                o[(size_t)row * 512 + h * 64 + cbv * 16 + lr] =
                    (__bf16)(acc[frag][cbv][r] * inv);
        }
    }
}

// ---------------------------------------------------------------------------
// Kernel 5: output projection GEMM. 384 blocks. K=512.
__global__ __launch_bounds__(256) void out_gemm_kernel(const __bf16* __restrict__ ob,
                                                       const __bf16* __restrict__ wot,
                                                       const float* __restrict__ bo,
                                                       float* __restrict__ out) {
    __shared__ __align__(16) __bf16 abuf[2 * 4096];
    __shared__ __align__(16) __bf16 bbuf[2 * 4096];

    const int bid = blockIdx.x;
    const int vb = (bid & 7) * 48 + (bid >> 3);
    const int by = vb % 6, bx = vb / 6;

    f32x4 acc[4][4] = {};
    gemm_tile_main<16>(ob, 512, bx * 128, wot, 512, by * 128, abuf, bbuf, acc);

    const int lane = threadIdx.x & 63, wave = threadIdx.x >> 6;
    const int lr = lane & 15, lg = lane >> 4;
    const int wr = wave >> 1, wc = wave & 1;

#pragma unroll
    for (int n = 0; n < 4; ++n) {
        const int col = by * 128 + wc * 64 + n * 16 + lr;
        const float bias = bo[col];
#pragma unroll
        for (int m = 0; m < 4; ++m) {
            const int row0 = bx * 128 + wr * 64 + m * 16 + lg * 4;
#pragma unroll
            for (int r = 0; r < 4; ++r)
                out[(size_t)(row0 + r) * 768 + col] = acc[m][n][r] + bias;
        }
    }
}

// ---------------------------------------------------------------------------
extern "C" void kernel_launch(void* const* d_in, const int* in_sizes, int n_in,
                              void* d_out, int out_size, void* d_ws, size_t ws_size,
                              hipStream_t stream) {
    const float* x  = (const float*)d_in[0];
    const float* Wq = (const float*)d_in[1];
    const float* Wk = (const float*)d_in[2];
    const float* Wv = (const float*)d_in[3];
    const float* Wo = (const float*)d_in[4];
    const float* bo = (const float*)d_in[5];
    float* out = (float*)d_out;

    char* ws = (char*)d_ws;
    __bf16* xb  = (__bf16*)(ws);                                  // 12,582,912
    __bf16* wt  = (__bf16*)(ws + 12582912);                       //  2,359,296
    __bf16* wot = (__bf16*)(ws + 12582912 + 2359296);             //    786,432
    char*   p0  = ws + 12582912 + 2359296 + 786432;               // 15,728,640
    __bf16* qw  = (__bf16*)(p0);                                  //  8,388,608
    __bf16* kw  = (__bf16*)(p0 + 8388608);
    __bf16* vtw = (__bf16*)(p0 + 2 * (size_t)8388608);
    __bf16* obf = (__bf16*)(p0 + 3 * (size_t)8388608);
    // total ws use: 49,283,072 bytes

    cvt_x_kernel<<<6144, 256, 0, stream>>>(x, xb, MROWS_ * DIM_ / 4);
    transpose_w_kernel<<<384, 256, 0, stream>>>(Wq, Wk, Wv, Wo, wt, wot);
    qkv_gemm_kernel<<<768, 256, 0, stream>>>(xb, wt, qw, kw, vtw);
    attn_kernel<<<512, 256, 0, stream>>>(qw, kw, vtw, obf);
    out_gemm_kernel<<<384, 256, 0, stream>>>(obf, wot, bo, out);
}